// Round 13
// baseline (1171.758 us; speedup 1.0000x reference)
//
#include <hip/hip_runtime.h>
#include <hip/hip_bf16.h>

// DTGCN: B=16,N=256,T=64,W=12,H=64,ED=64,S=5,C=4,E=2048, FG=76
// R13 = R12 minus the stray placeholder write (LDS overflow + race on s_dfhr).
// Barrier-free data-flow sync: per-phase tags (de/deg/h = step number),
// wave-polled; single-buffered exchanges proven safe by transitive tag deps.
// MFMA fragments read DIRECTLY from sc global (2x u64 loads) — no LDS restage.

typedef unsigned short u16;
typedef unsigned int u32;
typedef unsigned long long u64;
typedef __attribute__((ext_vector_type(8))) short bf16x8;
typedef __attribute__((ext_vector_type(4))) float f32x4;

#define B_ 16
#define N_ 256
#define T_ 64
#define W_ 12
#define S_ 5
#define E_ 2048
#define FG_ 76
#define G_ 16

__device__ __forceinline__ float b2f(u16 u) {
  union { u32 i; float f; } v; v.i = ((u32)u) << 16; return v.f;
}
__device__ __forceinline__ u16 f2b(float f) {
  union { float f; u32 i; } v; v.f = f;
  u32 x = v.i; x += 0x7fff + ((x >> 16) & 1); return (u16)(x >> 16);
}
__device__ __forceinline__ float ftanh(float x) {
  float e = __expf(-2.f * fabsf(x));
  float t = (1.f - e) / (1.f + e);
  return x < 0.f ? -t : t;
}
__device__ __forceinline__ float fsigm(float x) { return 1.f / (1.f + __expf(-x)); }
__device__ __forceinline__ float cvload(const void* p, int i, int f) {
  return f ? ((const float*)p)[i] : b2f(((const u16*)p)[i]);
}
__device__ __forceinline__ float gld(const float* p) {
  return __hip_atomic_load(p, __ATOMIC_RELAXED, __HIP_MEMORY_SCOPE_SYSTEM);
}
__device__ __forceinline__ void gst(float* p, float v) {
  __hip_atomic_store(p, v, __ATOMIC_RELAXED, __HIP_MEMORY_SCOPE_SYSTEM);
}
__device__ __forceinline__ u64 gld64(const u64* p) {
  return __hip_atomic_load(p, __ATOMIC_RELAXED, __HIP_MEMORY_SCOPE_SYSTEM);
}
__device__ __forceinline__ void gst64(u64* p, u64 v) {
  __hip_atomic_store(p, v, __ATOMIC_RELAXED, __HIP_MEMORY_SCOPE_SYSTEM);
}
__device__ __forceinline__ u32 gldu(const u32* p) {
  return __hip_atomic_load(p, __ATOMIC_RELAXED, __HIP_MEMORY_SCOPE_SYSTEM);
}
__device__ __forceinline__ f32x4 mfma16(bf16x8 a, bf16x8 b, f32x4 c) {
  return __builtin_amdgcn_mfma_f32_16x16x32_bf16(a, b, c, 0, 0, 0);
}
__device__ __forceinline__ bf16x8 ldfrag(const u16* p) { return *(const bf16x8*)p; }
__device__ __forceinline__ bf16x8 ldfrag_g(const u64* row, int off64) {
  union { u64 q[2]; bf16x8 f; } u;
  u.q[0] = gld64(row + off64);
  u.q[1] = gld64(row + off64 + 1);
  return u.f;
}

struct Params {
  const void *x0, *ew0, *gw0, *gb0, *w10, *b10, *w20, *b20;
  const void *wzc0, *bzc0, *wzl0, *bzl0, *wrc0, *brc0, *wrl0, *brl0;
  const void *whc0, *bhc0, *whl0, *bhl0, *clsw0, *clsb0;
  const int* eidx;
  float *xf, *ewf, *gwf, *gbf, *b1f, *b2ff;
  float *wzcf, *bzcf, *wzlf, *bzlf, *wrcf, *brcf, *wrlf, *brlf;
  float *whcf, *bhcf, *whlf, *bhlf, *clswf, *clsbf;
  u16 *w1h, *w2h;
  float *AnT, *dinvS, *uvF, *h, *degsum, *Eh, *Ascr;
  u64 *de1g, *de2g, *xTp, *hgpT, *zrow;
  u32 *tags;
  int *flag;
  void* out;
};

// wave-polls 16 tags (one 64B line); all lanes load tg[lane&15]
__device__ __forceinline__ void wtag(const u32* tg, u32 target) {
  const int k = threadIdx.x & 15;
  while (!__all((int)(gldu(&tg[k]) >= target)))
    __builtin_amdgcn_s_sleep(1);
}
__device__ __forceinline__ void ptag(u32* tg, int wg, u32 val) {
  if (threadIdx.x == 0)
    __hip_atomic_store(&tg[wg], val, __ATOMIC_RELAXED, __HIP_MEMORY_SCOPE_SYSTEM);
}

// ================= dtype detect + convert =================
__global__ void k_detect(Params p) {
  if (threadIdx.x == 0) {
    const u16* q = (const u16*)p.x0;
    int c = 0;
    for (int i = 0; i < 256; ++i) {
      int ex = (q[i] >> 7) & 0xff;
      c += (ex >= 110 && ex <= 135);
    }
    *p.flag = (c < 200) ? 1 : 0;
  }
}

__global__ void k_convert(Params p) {
  const int f = *p.flag;
  const int blk = blockIdx.x, tid = threadIdx.x;
  if (blk < 32) {
    const int base = blk * 8192;
    for (int i = tid; i < 8192; i += 256) p.xf[base + i] = cvload(p.x0, base + i, f);
    return;
  }
  if (blk == 51) { for (int i = tid; i < 4096; i += 256) p.w1h[i] = f ? f2b(((const float*)p.w10)[i]) : ((const u16*)p.w10)[i]; return; }
  if (blk == 52) { for (int i = tid; i < 4096; i += 256) p.w2h[i] = f ? f2b(((const float*)p.w20)[i]) : ((const u16*)p.w20)[i]; return; }
  const void* src = nullptr; float* dst = nullptr; int n = 0;
  switch (blk) {
    case 32: src = p.ew0;  dst = p.ewf;  n = E_;      break;
    case 33: src = p.gw0;  dst = p.gwf;  n = FG_ * 64; break;
    case 34: src = p.gb0;  dst = p.gbf;  n = 64;      break;
    case 35: src = p.b10;  dst = p.b1f;  n = 64;      break;
    case 36: src = p.b20;  dst = p.b2ff; n = 64;      break;
    case 37: src = p.wzc0; dst = p.wzcf; n = 64;      break;
    case 38: src = p.bzc0; dst = p.bzcf; n = 64;      break;
    case 39: src = p.wzl0; dst = p.wzlf; n = 8192;    break;
    case 40: src = p.bzl0; dst = p.bzlf; n = 64;      break;
    case 41: src = p.wrc0; dst = p.wrcf; n = 64;      break;
    case 42: src = p.brc0; dst = p.brcf; n = 64;      break;
    case 43: src = p.wrl0; dst = p.wrlf; n = 8192;    break;
    case 44: src = p.brl0; dst = p.brlf; n = 64;      break;
    case 45: src = p.whc0; dst = p.whcf; n = 64;      break;
    case 46: src = p.bhc0; dst = p.bhcf; n = 64;      break;
    case 47: src = p.whl0; dst = p.whlf; n = 8192;    break;
    case 48: src = p.bhl0; dst = p.bhlf; n = 64;      break;
    case 49: src = p.clsw0; dst = p.clswf; n = 65536; break;
    case 50: src = p.clsb0; dst = p.clsbf; n = 4;     break;
    default: return;
  }
  for (int i = tid; i < n; i += 256) dst[i] = cvload(src, i, f);
}

// x transpose: xTp[b][t] = 256 i as bf16 (64 u64 per row)
__global__ void k_xt(Params p) {
  __shared__ float tile[64 * 65];
  const int b = blockIdx.x, tid = threadIdx.x;
  u32* xT32 = (u32*)p.xTp;
  for (int chunk = 0; chunk < 4; ++chunk) {
    __syncthreads();
    const int r = tid >> 2, tq = (tid & 3) * 16;
    #pragma unroll
    for (int q = 0; q < 16; ++q)
      tile[r * 65 + tq + q] = p.xf[((size_t)b * N_ + chunk * 64 + r) * T_ + tq + q];
    __syncthreads();
    #pragma unroll
    for (int q = 0; q < 8; ++q) {
      const int idx = q * 256 + tid;
      const int t = idx >> 5, c = idx & 31;
      u32 v = (u32)f2b(tile[(2 * c) * 65 + t]) | ((u32)f2b(tile[(2 * c + 1) * 65 + t]) << 16);
      xT32[(size_t)(b * 64 + t) * 128 + chunk * 32 + c] = v;
    }
  }
}

// ================= init kernels =================
__global__ void k_scatter(Params p) {
  for (int e = threadIdx.x; e < E_; e += 256) {
    int s = p.eidx[e], d = p.eidx[E_ + e];
    atomicAdd(&p.Ascr[s * N_ + d], p.ewf[e]);
  }
}
__global__ void k_deg(Params p) {
  int j = threadIdx.x;
  float dg = 1.f;
  for (int i = 0; i < N_; ++i) dg += p.Ascr[i * N_ + j];
  p.dinvS[j] = rsqrtf(dg);
}
__global__ void k_ant(Params p) {
  int i = blockIdx.x, j = threadIdx.x;
  float a = p.Ascr[i * N_ + j] + (i == j ? 1.f : 0.f);
  p.AnT[j * N_ + i] = p.dinvS[i] * a * p.dinvS[j];
}
__global__ void k_uv(Params p) {
  int e = threadIdx.x; if (e >= 64) return;
  float uz = 0, vz = 0, ur = 0, vr = 0, uh = 0, vh = 0;
  for (int f = 0; f < 64; ++f) {
    float wz = p.wzlf[f * 64 + e], wr = p.wrlf[f * 64 + e], wh = p.whlf[f * 64 + e];
    uz += p.wzcf[f] * wz; vz += p.bzcf[f] * wz;
    ur += p.wrcf[f] * wr; vr += p.brcf[f] * wr;
    uh += p.whcf[f] * wh; vh += p.bhcf[f] * wh;
  }
  p.uvF[0 * 64 + e] = uz; p.uvF[1 * 64 + e] = vz + p.bzlf[e];
  p.uvF[2 * 64 + e] = ur; p.uvF[3 * 64 + e] = vr + p.brlf[e];
  p.uvF[4 * 64 + e] = uh; p.uvF[5 * 64 + e] = vh + p.bhlf[e];
}

// ================= main persistent kernel =================
__global__ void __launch_bounds__(256) dtgcn_main(Params p) {
  __shared__ __align__(16) u16 s_gwF[64 * 104];  // gw^T [e][k]: k0..63=h, 64..75=win, zero to 96
  __shared__ __align__(16) u16 s_w1T[64 * 72], s_w2T[64 * 72];
  __shared__ __align__(16) u16 s_gzT[64 * 72], s_grT[64 * 72], s_ghT[64 * 72];
  __shared__ __align__(16) u16 s_antO1[16 * 264], s_antO2[16 * 264];
  __shared__ __align__(16) u16 s_m1[16 * 104];
  __shared__ float s_msum[16 * 257];
  __shared__ __align__(16) u16 s_de1I[16 * 72], s_de2I[16 * 72];
  __shared__ __align__(16) u16 s_hbf[16 * 72];
  __shared__ __align__(16) u16 s_dfhr[16 * 72];
  __shared__ float s_part[256];
  __shared__ float s_colv[16], s_degacc[16];
  __shared__ float s_y[256], s_dinv[256], s_s[16];
  __shared__ float s_uv[384], s_gb[64], s_b1[64], s_b2[64];

  const int b = blockIdx.x & 15;
  const int wg = blockIdx.x >> 4;
  const int tid = threadIdx.x;
  const int lane = tid & 63;
  const int wv = tid >> 6;
  const int l = lane & 15;
  const int quad = lane >> 4;
  const int r0 = wg * 16;

  // ---- one-time LDS init ----
  for (int idx = tid; idx < 64 * 104; idx += 256) {
    const int ee = idx / 104, k = idx - ee * 104;
    u16 v = 0;
    if (k < 64) v = f2b(p.gwf[(12 + k) * 64 + ee]);
    else if (k < 76) v = f2b(p.gwf[(k - 64) * 64 + ee]);
    s_gwF[ee * 104 + k] = v;
  }
  for (int idx = tid; idx < 4096; idx += 256) {
    const int ee = idx >> 6, ff = idx & 63;
    s_w1T[ee * 72 + ff] = p.w1h[ff * 64 + ee];
    s_w2T[ee * 72 + ff] = p.w2h[ff * 64 + ee];
    s_gzT[ee * 72 + ff] = f2b(p.wzlf[4096 + ff * 64 + ee]);
    s_grT[ee * 72 + ff] = f2b(p.wrlf[4096 + ff * 64 + ee]);
    s_ghT[ee * 72 + ff] = f2b(p.whlf[4096 + ff * 64 + ee]);
    const int j = idx >> 8, i = idx & 255;
    float a = p.AnT[(r0 + j) * N_ + i];
    u16 hi = f2b(a);
    s_antO1[j * 264 + i] = hi;
    s_antO2[j * 264 + i] = f2b(a - b2f(hi));
  }
  for (int idx = tid; idx < 16 * 257; idx += 256) s_msum[idx] = 0.f;
  for (int idx = tid; idx < 16 * 72; idx += 256) s_hbf[idx] = 0;
  for (int idx = tid; idx < 16 * 104; idx += 256) s_m1[idx] = 0;
  for (int idx = tid; idx < 384; idx += 256) s_uv[idx] = p.uvF[idx];
  if (tid < 64) { s_gb[tid] = p.gbf[tid]; s_b1[tid] = p.b1f[tid]; s_b2[tid] = p.b2ff[tid]; }
  if (tid < 16) s_degacc[tid] = 0.f;
  __syncthreads();

  u64* de1g = p.de1g + (size_t)b * N_ * 16;       // [row i][16 u64]
  u64* de2g = p.de2g + (size_t)b * N_ * 16;
  u64* hgpb = p.hgpT + (size_t)b * 64 * 64;       // h^T [k][64 u64]
  const u64* xTb = p.xTp + (size_t)b * 64 * 64;   // x^T [t][64 u64]
  const u64* zrow = p.zrow;
  float* hb   = p.h + (size_t)b * N_ * 64;
  float* degb = p.degsum + (size_t)b * N_;
  u32* tgDe = p.tags + b * 64;        // 16 u32 each, 64-B lines
  u32* tgDg = p.tags + b * 64 + 16;
  u32* tgH  = p.tags + b * 64 + 32;

  float hreg[4] = {0.f, 0.f, 0.f, 0.f};
  const int e = wv * 16 + l;

  for (int t = 0; t < T_; ++t) {
    // ---------- phase A: M1 = A^T_own @ It (B-frags direct global); df; de ----------
    wtag(tgH, (u32)t);   // h(t-1) strips visible (trivial at t=0)
    {
      for (int nt = wv; nt < 5; nt += 4) {
        const int k = nt * 16 + l;
        const u64* rowp;
        if (k < 64) rowp = hgpb + (size_t)k * 64;
        else {
          const int tx = t - (W_ - 1) + (k - 64);
          rowp = (k < 76 && tx >= 0) ? (xTb + (size_t)tx * 64) : zrow;
        }
        f32x4 acc = {0.f, 0.f, 0.f, 0.f};
        #pragma unroll
        for (int ch = 0; ch < 8; ++ch) {
          bf16x8 bfr = ldfrag_g(rowp, ch * 8 + quad * 2);
          const int io = ch * 32 + quad * 8;
          acc = mfma16(ldfrag(&s_antO1[l * 264 + io]), bfr, acc);
          acc = mfma16(ldfrag(&s_antO2[l * 264 + io]), bfr, acc);
        }
        #pragma unroll
        for (int r = 0; r < 4; ++r)
          s_m1[(quad * 4 + r) * 104 + nt * 16 + l] = f2b(acc[r]);
      }
      __syncthreads();
      // df[j][e] = M1 @ gw + gb : K=96 (cols >=80 zero via gwF)
      {
        f32x4 dfa = {0.f, 0.f, 0.f, 0.f};
        #pragma unroll
        for (int ks = 0; ks < 3; ++ks) {
          bf16x8 afr = ldfrag(&s_m1[l * 104 + ks * 32 + quad * 8]);
          dfa = mfma16(afr, ldfrag(&s_gwF[e * 104 + ks * 32 + quad * 8]), dfa);
        }
        #pragma unroll
        for (int r = 0; r < 4; ++r)
          s_dfhr[(quad * 4 + r) * 72 + e] = f2b(dfa[r] + s_gb[e]);
      }
      __syncthreads();
      // de1/de2 (columns e)
      {
        f32x4 E1, E2;
        #pragma unroll
        for (int r = 0; r < 4; ++r) { E1[r] = s_b1[e]; E2[r] = s_b2[e]; }
        #pragma unroll
        for (int ks = 0; ks < 2; ++ks) {
          bf16x8 afr = ldfrag(&s_dfhr[l * 72 + ks * 32 + quad * 8]);
          E1 = mfma16(afr, ldfrag(&s_w1T[e * 72 + ks * 32 + quad * 8]), E1);
          E2 = mfma16(afr, ldfrag(&s_w2T[e * 72 + ks * 32 + quad * 8]), E2);
        }
        #pragma unroll
        for (int r = 0; r < 4; ++r) {
          s_de1I[(quad * 4 + r) * 72 + e] = f2b(ftanh(E1[r]));
          s_de2I[(quad * 4 + r) * 72 + e] = f2b(ftanh(E2[r]));
        }
      }
      __syncthreads();
      // publish own de strips (u64)
      {
        const int row = tid >> 4, c = tid & 15;
        u64 v1 = *(const u64*)&s_de1I[row * 72 + c * 4];
        u64 v2 = *(const u64*)&s_de2I[row * 72 + c * 4];
        gst64(&de1g[(size_t)(r0 + row) * 16 + c], v1);
        gst64(&de2g[(size_t)(r0 + row) * 16 + c], v2);
      }
      __syncthreads();
      ptag(tgDe, wg, (u32)(t + 1));
    }

    // ---------- P3: Et column strip; A-frags direct global; Eh/Msum/deg ----------
    wtag(tgDe, (u32)(t + 1));
    {
      const int sidx = t % S_;
      float* Ehc = p.Eh + (size_t)(b * S_ + sidx) * N_ * N_;  // [own j][i]
      if (tid < 16) s_colv[tid] = 0.f;
      bf16x8 bq1[2], bq2[2];
      #pragma unroll
      for (int ks = 0; ks < 2; ++ks) {
        bq1[ks] = ldfrag(&s_de1I[l * 72 + ks * 32 + quad * 8]);
        bq2[ks] = ldfrag(&s_de2I[l * 72 + ks * 32 + quad * 8]);
      }
      __syncthreads();   // s_colv zeroed before adds
      float dcacc = 0.f;
      #pragma unroll
      for (int q = 0; q < 4; ++q) {
        const int mt = wv * 4 + q;
        const u64* r1 = de1g + (size_t)(mt * 16 + l) * 16;
        const u64* r2 = de2g + (size_t)(mt * 16 + l) * 16;
        f32x4 D1 = {0.f, 0.f, 0.f, 0.f}, D2 = {0.f, 0.f, 0.f, 0.f};
        #pragma unroll
        for (int ks = 0; ks < 2; ++ks) {
          bf16x8 a1 = ldfrag_g(r1, ks * 8 + quad * 2);
          bf16x8 a2 = ldfrag_g(r2, ks * 8 + quad * 2);
          D1 = mfma16(a1, bq2[ks], D1);   // de1_i . de2_j
          D2 = mfma16(a2, bq1[ks], D2);   // de2_i . de1_j
        }
        #pragma unroll
        for (int r = 0; r < 4; ++r) {
          const int i = mt * 16 + quad * 4 + r;
          float d = ftanh(D1[r] - D2[r]);
          float eN = fmaxf(d, 0.f);
          float old = Ehc[(r0 + l) * N_ + i];
          float dd = eN - old;
          Ehc[(r0 + l) * N_ + i] = eN;
          s_msum[l * 257 + i] += dd;
          dcacc += dd;
        }
      }
      dcacc += __shfl_xor(dcacc, 16);
      dcacc += __shfl_xor(dcacc, 32);
      if (lane < 16) atomicAdd(&s_colv[lane], dcacc);
      __syncthreads();
      if (tid < 16) {
        float nd = s_degacc[tid] + s_colv[tid];
        s_degacc[tid] = nd;
        gst(&degb[r0 + tid], nd);
      }
      __syncthreads();
      ptag(tgDg, wg, (u32)(t + 1));
    }

    // ---------- P4: dinv/y, s, GRU, h publish ----------
    wtag(tgDg, (u32)(t + 1));
    {
      const float cnt = (float)((t + 1 < S_) ? (t + 1) : S_);
      const float invc = 1.f / cnt;
      {
        float dg = 1.f + gld(&degb[tid]) * invc;
        float di = rsqrtf(dg);
        float xv = p.xf[((size_t)b * N_ + tid) * T_ + t];
        s_dinv[tid] = di;
        s_y[tid] = di * xv;
      }
      __syncthreads();
      {
        const int jl = tid & 15, c = tid >> 4;
        float part = 0.f;
        #pragma unroll
        for (int k = 0; k < 16; ++k)
          part += s_msum[jl * 257 + c * 16 + k] * s_y[c * 16 + k];
        s_part[c * 16 + jl] = part;
      }
      __syncthreads();
      if (tid < 16) {
        float tot = 0.f;
        for (int k = 0; k < 16; ++k) tot += s_part[k * 16 + tid];
        const int j = r0 + tid;
        s_s[tid] = s_dinv[j] * (tot * invc + s_y[j]);
      }
      __syncthreads();
      float sv[4];
      #pragma unroll
      for (int r = 0; r < 4; ++r) sv[r] = s_s[quad * 4 + r];
      // z gate
      f32x4 az;
      #pragma unroll
      for (int r = 0; r < 4; ++r) az[r] = s_uv[0 * 64 + e] * sv[r] + s_uv[1 * 64 + e];
      #pragma unroll
      for (int ks = 0; ks < 2; ++ks) {
        bf16x8 afr = ldfrag(&s_hbf[l * 72 + ks * 32 + quad * 8]);
        az = mfma16(afr, ldfrag(&s_gzT[e * 72 + ks * 32 + quad * 8]), az);
      }
      float zz[4];
      #pragma unroll
      for (int r = 0; r < 4; ++r) zz[r] = fsigm(az[r]);
      // r gate
      f32x4 ar_;
      #pragma unroll
      for (int r = 0; r < 4; ++r) ar_[r] = s_uv[2 * 64 + e] * sv[r] + s_uv[3 * 64 + e];
      #pragma unroll
      for (int ks = 0; ks < 2; ++ks) {
        bf16x8 afr = ldfrag(&s_hbf[l * 72 + ks * 32 + quad * 8]);
        ar_ = mfma16(afr, ldfrag(&s_grT[e * 72 + ks * 32 + quad * 8]), ar_);
      }
      #pragma unroll
      for (int r = 0; r < 4; ++r)
        s_dfhr[(quad * 4 + r) * 72 + e] = f2b(hreg[r] * fsigm(ar_[r]));
      __syncthreads();
      // candidate
      f32x4 ah;
      #pragma unroll
      for (int r = 0; r < 4; ++r) ah[r] = s_uv[4 * 64 + e] * sv[r] + s_uv[5 * 64 + e];
      #pragma unroll
      for (int ks = 0; ks < 2; ++ks) {
        bf16x8 afr = ldfrag(&s_dfhr[l * 72 + ks * 32 + quad * 8]);
        ah = mfma16(afr, ldfrag(&s_ghT[e * 72 + ks * 32 + quad * 8]), ah);
      }
      #pragma unroll
      for (int r = 0; r < 4; ++r) {
        float ht = ftanh(ah[r]);
        hreg[r] = zz[r] * hreg[r] + (1.f - zz[r]) * ht;
      }
      #pragma unroll
      for (int r = 0; r < 4; ++r)
        s_hbf[(quad * 4 + r) * 72 + e] = f2b(hreg[r]);
      if (t == T_ - 1) {
        #pragma unroll
        for (int r = 0; r < 4; ++r)
          hb[(r0 + quad * 4 + r) * 64 + e] = hreg[r];
      }
      __syncthreads();
      // publish h^T strip: hgpT[k][own 4 u64]
      {
        const int k = tid >> 2, c4 = tid & 3;
        u64 v = (u64)s_hbf[(c4 * 4 + 0) * 72 + k]
              | ((u64)s_hbf[(c4 * 4 + 1) * 72 + k] << 16)
              | ((u64)s_hbf[(c4 * 4 + 2) * 72 + k] << 32)
              | ((u64)s_hbf[(c4 * 4 + 3) * 72 + k] << 48);
        gst64(&hgpb[(size_t)k * 64 + (r0 >> 2) + c4], v);
      }
      __syncthreads();
      ptag(tgH, wg, (u32)(t + 1));
    }
  }
}

// ================= classifier =================
__global__ void k_cls(Params p) {
  __shared__ float red[256][4];
  const int b = blockIdx.x, i = threadIdx.x;
  const float* hr = p.h + ((size_t)b * N_ + i) * 64;
  const float* w = p.clswf + (size_t)i * 64 * 4;
  float a0 = 0, a1 = 0, a2 = 0, a3 = 0;
  for (int f = 0; f < 64; ++f) {
    float hv = hr[f];
    a0 += hv * w[f * 4 + 0]; a1 += hv * w[f * 4 + 1];
    a2 += hv * w[f * 4 + 2]; a3 += hv * w[f * 4 + 3];
  }
  red[i][0] = a0; red[i][1] = a1; red[i][2] = a2; red[i][3] = a3;
  __syncthreads();
  for (int st = 128; st > 0; st >>= 1) {
    if (i < st) {
      red[i][0] += red[i + st][0]; red[i][1] += red[i + st][1];
      red[i][2] += red[i + st][2]; red[i][3] += red[i + st][3];
    }
    __syncthreads();
  }
  if (i < 4) {
    float v = red[0][i] + p.clsbf[i];
    if (*p.flag) ((float*)p.out)[b * 4 + i] = v;
    else         ((u16*)p.out)[b * 4 + i] = f2b(v);
  }
}

extern "C" void kernel_launch(void* const* d_in, const int* in_sizes, int n_in,
                              void* d_out, int out_size, void* d_ws, size_t ws_size,
                              hipStream_t stream) {
  float* w = (float*)d_ws;
  size_t o = 0;
  auto alloc = [&](size_t n) { float* r = w + o; o += (n + 63) & ~(size_t)63; return r; };
  float* xf    = alloc(262144);
  float* ewf   = alloc(E_);
  float* gwf   = alloc(FG_ * 64);
  float* gbf   = alloc(64);
  float* b1f   = alloc(64);
  float* b2ff  = alloc(64);
  float* wzcf  = alloc(64); float* bzcf = alloc(64); float* wzlf = alloc(8192); float* bzlf = alloc(64);
  float* wrcf  = alloc(64); float* brcf = alloc(64); float* wrlf = alloc(8192); float* brlf = alloc(64);
  float* whcf  = alloc(64); float* bhcf = alloc(64); float* whlf = alloc(8192); float* bhlf = alloc(64);
  float* clswf = alloc(65536); float* clsbf = alloc(64);
  u16* w1h = (u16*)alloc(2048);
  u16* w2h = (u16*)alloc(2048);
  int* flag = (int*)alloc(64);
  float* AnT   = alloc(65536);
  float* dinvS = alloc(256);
  float* uvF   = alloc(384);
  u64* de1g = (u64*)alloc((size_t)B_ * N_ * 32);   // 16 u64/row
  u64* de2g = (u64*)alloc((size_t)B_ * N_ * 32);
  u64* xTp  = (u64*)alloc((size_t)B_ * 64 * 128);  // 64 u64/row
  const size_t zero_off = o;
  float* Ascr  = alloc((size_t)N_ * N_);
  float* h     = alloc((size_t)B_ * N_ * 64);
  u64*   hgpT  = (u64*)alloc((size_t)B_ * 64 * 128);
  float* degs  = alloc((size_t)B_ * N_);
  u64*   zrow  = (u64*)alloc(128);
  u32*   tags  = (u32*)alloc(B_ * 64);             // 256 B per batch
  float* Eh    = alloc((size_t)B_ * S_ * N_ * N_);
  if (ws_size < o * sizeof(float)) return;

  (void)hipMemsetAsync(w + zero_off, 0, (o - zero_off) * sizeof(float), stream);

  Params p;
  p.x0  = d_in[0];  p.ew0 = d_in[1];
  p.gw0 = d_in[2];  p.gb0 = d_in[3];
  p.w10 = d_in[4];  p.b10 = d_in[5];
  p.w20 = d_in[6];  p.b20 = d_in[7];
  p.wzc0 = d_in[8];  p.bzc0 = d_in[9];  p.wzl0 = d_in[10]; p.bzl0 = d_in[11];
  p.wrc0 = d_in[12]; p.brc0 = d_in[13]; p.wrl0 = d_in[14]; p.brl0 = d_in[15];
  p.whc0 = d_in[16]; p.bhc0 = d_in[17]; p.whl0 = d_in[18]; p.bhl0 = d_in[19];
  p.clsw0 = d_in[20]; p.clsb0 = d_in[21];
  p.eidx = (const int*)d_in[22];
  p.xf = xf; p.ewf = ewf; p.gwf = gwf; p.gbf = gbf; p.b1f = b1f; p.b2ff = b2ff;
  p.wzcf = wzcf; p.bzcf = bzcf; p.wzlf = wzlf; p.bzlf = bzlf;
  p.wrcf = wrcf; p.brcf = brcf; p.wrlf = wrlf; p.brlf = brlf;
  p.whcf = whcf; p.bhcf = bhcf; p.whlf = whlf; p.bhlf = bhlf;
  p.clswf = clswf; p.clsbf = clsbf; p.w1h = w1h; p.w2h = w2h;
  p.AnT = AnT; p.dinvS = dinvS; p.uvF = uvF;
  p.h = h; p.degsum = degs; p.Eh = Eh; p.Ascr = Ascr;
  p.de1g = de1g; p.de2g = de2g; p.xTp = xTp; p.hgpT = hgpT; p.zrow = zrow;
  p.tags = tags; p.flag = flag; p.out = d_out;

  k_detect<<<1, 64, 0, stream>>>(p);
  k_convert<<<53, 256, 0, stream>>>(p);
  k_xt<<<B_, 256, 0, stream>>>(p);
  k_scatter<<<1, 256, 0, stream>>>(p);
  k_deg<<<1, 256, 0, stream>>>(p);
  k_ant<<<N_, 256, 0, stream>>>(p);
  k_uv<<<1, 64, 0, stream>>>(p);

  void* args[] = { &p };
  hipError_t ce = hipLaunchCooperativeKernel((const void*)dtgcn_main,
                                             dim3(B_ * G_), dim3(256), args, 0, stream);
  if (ce != hipSuccess) {
    (void)hipGetLastError();
    dtgcn_main<<<dim3(B_ * G_), dim3(256), 0, stream>>>(p);
  }

  k_cls<<<B_, 256, 0, stream>>>(p);
}

// Round 14
// 950.680 us; speedup vs baseline: 1.2325x; 1.2325x over previous
//
#include <hip/hip_runtime.h>
#include <hip/hip_bf16.h>

// DTGCN: B=16,N=256,T=64,W=12,H=64,ED=64,S=5,C=4,E=2048, FG=76
// R14 = R11's batched LDS staging + R13's tag-based dataflow sync.
// Tags (de/deg/h = step number) wave-polled; producers never block.
// All MFMA operands fed from LDS; sc loads batched into registers first.
// P3 owns columns (Msum pure LDS); phase A: df=(A^T_own.It)@gw, K=96 padded.

typedef unsigned short u16;
typedef unsigned int u32;
typedef unsigned long long u64;
typedef __attribute__((ext_vector_type(8))) short bf16x8;
typedef __attribute__((ext_vector_type(4))) float f32x4;

#define B_ 16
#define N_ 256
#define T_ 64
#define W_ 12
#define S_ 5
#define E_ 2048
#define FG_ 76
#define G_ 16

__device__ __forceinline__ float b2f(u16 u) {
  union { u32 i; float f; } v; v.i = ((u32)u) << 16; return v.f;
}
__device__ __forceinline__ u16 f2b(float f) {
  union { float f; u32 i; } v; v.f = f;
  u32 x = v.i; x += 0x7fff + ((x >> 16) & 1); return (u16)(x >> 16);
}
__device__ __forceinline__ float ftanh(float x) {
  float e = __expf(-2.f * fabsf(x));
  float t = (1.f - e) / (1.f + e);
  return x < 0.f ? -t : t;
}
__device__ __forceinline__ float fsigm(float x) { return 1.f / (1.f + __expf(-x)); }
__device__ __forceinline__ float cvload(const void* p, int i, int f) {
  return f ? ((const float*)p)[i] : b2f(((const u16*)p)[i]);
}
__device__ __forceinline__ float gld(const float* p) {
  return __hip_atomic_load(p, __ATOMIC_RELAXED, __HIP_MEMORY_SCOPE_SYSTEM);
}
__device__ __forceinline__ void gst(float* p, float v) {
  __hip_atomic_store(p, v, __ATOMIC_RELAXED, __HIP_MEMORY_SCOPE_SYSTEM);
}
__device__ __forceinline__ u64 gld64(const u64* p) {
  return __hip_atomic_load(p, __ATOMIC_RELAXED, __HIP_MEMORY_SCOPE_SYSTEM);
}
__device__ __forceinline__ void gst64(u64* p, u64 v) {
  __hip_atomic_store(p, v, __ATOMIC_RELAXED, __HIP_MEMORY_SCOPE_SYSTEM);
}
__device__ __forceinline__ u32 gldu(const u32* p) {
  return __hip_atomic_load(p, __ATOMIC_RELAXED, __HIP_MEMORY_SCOPE_SYSTEM);
}
__device__ __forceinline__ f32x4 mfma16(bf16x8 a, bf16x8 b, f32x4 c) {
  return __builtin_amdgcn_mfma_f32_16x16x32_bf16(a, b, c, 0, 0, 0);
}
__device__ __forceinline__ bf16x8 ldfrag(const u16* p) { return *(const bf16x8*)p; }

struct Params {
  const void *x0, *ew0, *gw0, *gb0, *w10, *b10, *w20, *b20;
  const void *wzc0, *bzc0, *wzl0, *bzl0, *wrc0, *brc0, *wrl0, *brl0;
  const void *whc0, *bhc0, *whl0, *bhl0, *clsw0, *clsb0;
  const int* eidx;
  float *xf, *ewf, *gwf, *gbf, *b1f, *b2ff;
  float *wzcf, *bzcf, *wzlf, *bzlf, *wrcf, *brcf, *wrlf, *brlf;
  float *whcf, *bhcf, *whlf, *bhlf, *clswf, *clsbf;
  u16 *w1h, *w2h;
  float *AnT, *dinvS, *uvF, *h, *degsum, *Eh, *Ascr;
  u64 *de1g, *de2g, *xTp, *hgpT;
  u32 *tags;
  int *flag;
  void* out;
};

// wave-polls 16 tags (one 64B line); all lanes load tg[lane&15]
__device__ __forceinline__ void wtag(const u32* tg, u32 target) {
  const int k = threadIdx.x & 15;
  while (!__all((int)(gldu(&tg[k]) >= target)))
    __builtin_amdgcn_s_sleep(1);
}
__device__ __forceinline__ void ptag(u32* tg, int wg, u32 val) {
  if (threadIdx.x == 0)
    __hip_atomic_store(&tg[wg], val, __ATOMIC_RELAXED, __HIP_MEMORY_SCOPE_SYSTEM);
}

// ================= dtype detect + convert =================
__global__ void k_detect(Params p) {
  if (threadIdx.x == 0) {
    const u16* q = (const u16*)p.x0;
    int c = 0;
    for (int i = 0; i < 256; ++i) {
      int ex = (q[i] >> 7) & 0xff;
      c += (ex >= 110 && ex <= 135);
    }
    *p.flag = (c < 200) ? 1 : 0;
  }
}

__global__ void k_convert(Params p) {
  const int f = *p.flag;
  const int blk = blockIdx.x, tid = threadIdx.x;
  if (blk < 32) {
    const int base = blk * 8192;
    for (int i = tid; i < 8192; i += 256) p.xf[base + i] = cvload(p.x0, base + i, f);
    return;
  }
  if (blk == 51) { for (int i = tid; i < 4096; i += 256) p.w1h[i] = f ? f2b(((const float*)p.w10)[i]) : ((const u16*)p.w10)[i]; return; }
  if (blk == 52) { for (int i = tid; i < 4096; i += 256) p.w2h[i] = f ? f2b(((const float*)p.w20)[i]) : ((const u16*)p.w20)[i]; return; }
  const void* src = nullptr; float* dst = nullptr; int n = 0;
  switch (blk) {
    case 32: src = p.ew0;  dst = p.ewf;  n = E_;      break;
    case 33: src = p.gw0;  dst = p.gwf;  n = FG_ * 64; break;
    case 34: src = p.gb0;  dst = p.gbf;  n = 64;      break;
    case 35: src = p.b10;  dst = p.b1f;  n = 64;      break;
    case 36: src = p.b20;  dst = p.b2ff; n = 64;      break;
    case 37: src = p.wzc0; dst = p.wzcf; n = 64;      break;
    case 38: src = p.bzc0; dst = p.bzcf; n = 64;      break;
    case 39: src = p.wzl0; dst = p.wzlf; n = 8192;    break;
    case 40: src = p.bzl0; dst = p.bzlf; n = 64;      break;
    case 41: src = p.wrc0; dst = p.wrcf; n = 64;      break;
    case 42: src = p.brc0; dst = p.brcf; n = 64;      break;
    case 43: src = p.wrl0; dst = p.wrlf; n = 8192;    break;
    case 44: src = p.brl0; dst = p.brlf; n = 64;      break;
    case 45: src = p.whc0; dst = p.whcf; n = 64;      break;
    case 46: src = p.bhc0; dst = p.bhcf; n = 64;      break;
    case 47: src = p.whl0; dst = p.whlf; n = 8192;    break;
    case 48: src = p.bhl0; dst = p.bhlf; n = 64;      break;
    case 49: src = p.clsw0; dst = p.clswf; n = 65536; break;
    case 50: src = p.clsb0; dst = p.clsbf; n = 4;     break;
    default: return;
  }
  for (int i = tid; i < n; i += 256) dst[i] = cvload(src, i, f);
}

// x transpose: xTp[b][t] = 256 i as bf16 (64 u64 per row)
__global__ void k_xt(Params p) {
  __shared__ float tile[64 * 65];
  const int b = blockIdx.x, tid = threadIdx.x;
  u32* xT32 = (u32*)p.xTp;
  for (int chunk = 0; chunk < 4; ++chunk) {
    __syncthreads();
    const int r = tid >> 2, tq = (tid & 3) * 16;
    #pragma unroll
    for (int q = 0; q < 16; ++q)
      tile[r * 65 + tq + q] = p.xf[((size_t)b * N_ + chunk * 64 + r) * T_ + tq + q];
    __syncthreads();
    #pragma unroll
    for (int q = 0; q < 8; ++q) {
      const int idx = q * 256 + tid;
      const int t = idx >> 5, c = idx & 31;
      u32 v = (u32)f2b(tile[(2 * c) * 65 + t]) | ((u32)f2b(tile[(2 * c + 1) * 65 + t]) << 16);
      xT32[(size_t)(b * 64 + t) * 128 + chunk * 32 + c] = v;
    }
  }
}

// ================= init kernels =================
__global__ void k_scatter(Params p) {
  for (int e = threadIdx.x; e < E_; e += 256) {
    int s = p.eidx[e], d = p.eidx[E_ + e];
    atomicAdd(&p.Ascr[s * N_ + d], p.ewf[e]);
  }
}
__global__ void k_deg(Params p) {
  int j = threadIdx.x;
  float dg = 1.f;
  for (int i = 0; i < N_; ++i) dg += p.Ascr[i * N_ + j];
  p.dinvS[j] = rsqrtf(dg);
}
__global__ void k_ant(Params p) {
  int i = blockIdx.x, j = threadIdx.x;
  float a = p.Ascr[i * N_ + j] + (i == j ? 1.f : 0.f);
  p.AnT[j * N_ + i] = p.dinvS[i] * a * p.dinvS[j];
}
__global__ void k_uv(Params p) {
  int e = threadIdx.x; if (e >= 64) return;
  float uz = 0, vz = 0, ur = 0, vr = 0, uh = 0, vh = 0;
  for (int f = 0; f < 64; ++f) {
    float wz = p.wzlf[f * 64 + e], wr = p.wrlf[f * 64 + e], wh = p.whlf[f * 64 + e];
    uz += p.wzcf[f] * wz; vz += p.bzcf[f] * wz;
    ur += p.wrcf[f] * wr; vr += p.brcf[f] * wr;
    uh += p.whcf[f] * wh; vh += p.bhcf[f] * wh;
  }
  p.uvF[0 * 64 + e] = uz; p.uvF[1 * 64 + e] = vz + p.bzlf[e];
  p.uvF[2 * 64 + e] = ur; p.uvF[3 * 64 + e] = vr + p.brlf[e];
  p.uvF[4 * 64 + e] = uh; p.uvF[5 * 64 + e] = vh + p.bhlf[e];
}

// ================= main persistent kernel =================
__global__ void __launch_bounds__(256) dtgcn_main(Params p) {
  __shared__ __align__(16) u16 s_union[21120];   // A: ItT[80][264] / P3: j1,j2[128][72] / P4: s_part
  __shared__ __align__(16) u16 s_gwF[64 * 104];  // gw^T [e][k]: k0..63=h, 64..75=win, zero to 96
  __shared__ __align__(16) u16 s_w1T[64 * 72], s_w2T[64 * 72];
  __shared__ __align__(16) u16 s_gzT[64 * 72], s_grT[64 * 72], s_ghT[64 * 72];
  __shared__ __align__(16) u16 s_antO1[16 * 264], s_antO2[16 * 264];
  __shared__ __align__(16) u16 s_m1[16 * 104];
  __shared__ float s_msum[16 * 257];
  __shared__ __align__(16) u16 s_de1I[16 * 72], s_de2I[16 * 72];
  __shared__ __align__(16) u16 s_hbf[16 * 72];
  __shared__ __align__(16) u16 s_dfhr[16 * 72];
  __shared__ float s_colv[16], s_degacc[16];
  __shared__ float s_y[256], s_dinv[256], s_s[16];
  __shared__ float s_uv[384], s_gb[64], s_b1[64], s_b2[64];

  const int b = blockIdx.x & 15;
  const int wg = blockIdx.x >> 4;
  const int tid = threadIdx.x;
  const int lane = tid & 63;
  const int wv = tid >> 6;
  const int l = lane & 15;
  const int quad = lane >> 4;
  const int r0 = wg * 16;

  // ---- one-time LDS init ----
  for (int idx = tid; idx < 64 * 104; idx += 256) {
    const int ee = idx / 104, k = idx - ee * 104;
    u16 v = 0;
    if (k < 64) v = f2b(p.gwf[(12 + k) * 64 + ee]);
    else if (k < 76) v = f2b(p.gwf[(k - 64) * 64 + ee]);
    s_gwF[ee * 104 + k] = v;
  }
  for (int idx = tid; idx < 4096; idx += 256) {
    const int ee = idx >> 6, ff = idx & 63;
    s_w1T[ee * 72 + ff] = p.w1h[ff * 64 + ee];
    s_w2T[ee * 72 + ff] = p.w2h[ff * 64 + ee];
    s_gzT[ee * 72 + ff] = f2b(p.wzlf[4096 + ff * 64 + ee]);
    s_grT[ee * 72 + ff] = f2b(p.wrlf[4096 + ff * 64 + ee]);
    s_ghT[ee * 72 + ff] = f2b(p.whlf[4096 + ff * 64 + ee]);
    const int j = idx >> 8, i = idx & 255;
    float a = p.AnT[(r0 + j) * N_ + i];
    u16 hi = f2b(a);
    s_antO1[j * 264 + i] = hi;
    s_antO2[j * 264 + i] = f2b(a - b2f(hi));
  }
  for (int idx = tid; idx < 16 * 257; idx += 256) s_msum[idx] = 0.f;
  for (int idx = tid; idx < 16 * 72; idx += 256) s_hbf[idx] = 0;
  for (int idx = tid; idx < 16 * 104; idx += 256) s_m1[idx] = 0;
  for (int idx = 20064 + tid; idx < 21120; idx += 256) s_union[idx] = 0;  // ItT pad rows 76..79
  for (int idx = tid; idx < 384; idx += 256) s_uv[idx] = p.uvF[idx];
  if (tid < 64) { s_gb[tid] = p.gbf[tid]; s_b1[tid] = p.b1f[tid]; s_b2[tid] = p.b2ff[tid]; }
  if (tid < 16) s_degacc[tid] = 0.f;
  __syncthreads();

  u64* de1g = p.de1g + (size_t)b * N_ * 16;       // [row i][16 u64]
  u64* de2g = p.de2g + (size_t)b * N_ * 16;
  u64* hgpb = p.hgpT + (size_t)b * 64 * 64;       // h^T [k][64 u64]
  const u64* xTb = p.xTp + (size_t)b * 64 * 64;   // x^T [t][64 u64]
  float* hb   = p.h + (size_t)b * N_ * 64;
  float* degb = p.degsum + (size_t)b * N_;
  u32* tgDe = p.tags + b * 64;        // 16 u32 each, separate 64-B lines
  u32* tgDg = p.tags + b * 64 + 16;
  u32* tgH  = p.tags + b * 64 + 32;

  u16* s_itT = s_union;                 // [80][264] (phase A)
  u16* s_j1  = s_union;                 // [128][72] (P3 halves)
  u16* s_j2  = s_union + 9216;
  float* s_part = (float*)s_union;      // (P4)

  float hreg[4] = {0.f, 0.f, 0.f, 0.f};
  const int e = wv * 16 + l;

  for (int t = 0; t < T_; ++t) {
    // ---------- phase A: stage ItT; M1 = A^T_own @ It; df = M1@gw; de ----------
    {
      // x-window regs first (no tag dependency)
      u64 tw[3];
      #pragma unroll
      for (int q = 0; q < 3; ++q) {
        const int idx = q * 256 + tid;
        const int row = idx >> 6, c = idx & 63;
        const int tx = t - (W_ - 1) + row;
        tw[q] = (tx >= 0) ? gld64(&xTb[(size_t)tx * 64 + c]) : 0ull;
      }
      wtag(tgH, (u32)t);   // h(t-1) visible (trivial at t=0)
      u64 th[16];
      #pragma unroll
      for (int q = 0; q < 16; ++q) {
        const int idx = q * 256 + tid;
        const int row = idx >> 6, c = idx & 63;
        th[q] = gld64(&hgpb[(size_t)row * 64 + c]);
      }
      #pragma unroll
      for (int q = 0; q < 16; ++q) {
        const int idx = q * 256 + tid;
        const int row = idx >> 6, c = idx & 63;
        *(u64*)&s_itT[row * 264 + c * 4] = th[q];
      }
      #pragma unroll
      for (int q = 0; q < 3; ++q) {
        const int idx = q * 256 + tid;
        const int row = idx >> 6, c = idx & 63;
        *(u64*)&s_itT[(64 + row) * 264 + c * 4] = tw[q];
      }
      __syncthreads();
      // M1[j][kk]: 5 n-tiles of 16 over k=0..79, K=i (8 chunks), split-bf16 A
      for (int nt = wv; nt < 5; nt += 4) {
        f32x4 acc = {0.f, 0.f, 0.f, 0.f};
        #pragma unroll
        for (int ch = 0; ch < 8; ++ch) {
          const int io = ch * 32 + quad * 8;
          bf16x8 bfr = ldfrag(&s_itT[(nt * 16 + l) * 264 + io]);
          acc = mfma16(ldfrag(&s_antO1[l * 264 + io]), bfr, acc);
          acc = mfma16(ldfrag(&s_antO2[l * 264 + io]), bfr, acc);
        }
        #pragma unroll
        for (int r = 0; r < 4; ++r)
          s_m1[(quad * 4 + r) * 104 + nt * 16 + l] = f2b(acc[r]);
      }
      __syncthreads();
      // df[j][e] = M1 @ gw + gb : K=96 (cols >=80 zero)
      {
        f32x4 dfa = {0.f, 0.f, 0.f, 0.f};
        #pragma unroll
        for (int ks = 0; ks < 3; ++ks) {
          bf16x8 afr = ldfrag(&s_m1[l * 104 + ks * 32 + quad * 8]);
          dfa = mfma16(afr, ldfrag(&s_gwF[e * 104 + ks * 32 + quad * 8]), dfa);
        }
        #pragma unroll
        for (int r = 0; r < 4; ++r)
          s_dfhr[(quad * 4 + r) * 72 + e] = f2b(dfa[r] + s_gb[e]);
      }
      __syncthreads();
      // de1/de2 (columns e)
      {
        f32x4 E1, E2;
        #pragma unroll
        for (int r = 0; r < 4; ++r) { E1[r] = s_b1[e]; E2[r] = s_b2[e]; }
        #pragma unroll
        for (int ks = 0; ks < 2; ++ks) {
          bf16x8 afr = ldfrag(&s_dfhr[l * 72 + ks * 32 + quad * 8]);
          E1 = mfma16(afr, ldfrag(&s_w1T[e * 72 + ks * 32 + quad * 8]), E1);
          E2 = mfma16(afr, ldfrag(&s_w2T[e * 72 + ks * 32 + quad * 8]), E2);
        }
        #pragma unroll
        for (int r = 0; r < 4; ++r) {
          s_de1I[(quad * 4 + r) * 72 + e] = f2b(ftanh(E1[r]));
          s_de2I[(quad * 4 + r) * 72 + e] = f2b(ftanh(E2[r]));
        }
      }
      __syncthreads();
      // publish own de strips (u64)
      {
        const int row = tid >> 4, c = tid & 15;
        u64 v1 = *(const u64*)&s_de1I[row * 72 + c * 4];
        u64 v2 = *(const u64*)&s_de2I[row * 72 + c * 4];
        gst64(&de1g[(size_t)(r0 + row) * 16 + c], v1);
        gst64(&de2g[(size_t)(r0 + row) * 16 + c], v2);
      }
      __syncthreads();
      ptag(tgDe, wg, (u32)(t + 1));
    }

    // ---------- P3: Et column strip via LDS-staged MFMA; Eh/Msum/deg ----------
    {
      const int sidx = t % S_;
      float* Ehc = p.Eh + (size_t)(b * S_ + sidx) * N_ * N_;  // [own j][i]
      if (tid < 16) s_colv[tid] = 0.f;
      bf16x8 bq1[2], bq2[2];
      #pragma unroll
      for (int ks = 0; ks < 2; ++ks) {
        bq1[ks] = ldfrag(&s_de1I[l * 72 + ks * 32 + quad * 8]);
        bq2[ks] = ldfrag(&s_de2I[l * 72 + ks * 32 + quad * 8]);
      }
      wtag(tgDe, (u32)(t + 1));
      float dcacc = 0.f;
      for (int jh = 0; jh < 2; ++jh) {
        u64 t1[8], t2[8];
        #pragma unroll
        for (int q = 0; q < 8; ++q) {
          const int idx = q * 256 + tid;
          const int row = idx >> 4, c = idx & 15;
          t1[q] = gld64(&de1g[(size_t)(jh * 128 + row) * 16 + c]);
          t2[q] = gld64(&de2g[(size_t)(jh * 128 + row) * 16 + c]);
        }
        __syncthreads();   // prev contents of s_union consumed
        #pragma unroll
        for (int q = 0; q < 8; ++q) {
          const int idx = q * 256 + tid;
          const int row = idx >> 4, c = idx & 15;
          *(u64*)&s_j1[row * 72 + c * 4] = t1[q];
          *(u64*)&s_j2[row * 72 + c * 4] = t2[q];
        }
        __syncthreads();
        #pragma unroll
        for (int mt2 = 0; mt2 < 2; ++mt2) {
          const int mt = wv * 2 + mt2;          // i-tile within half (0..7)
          f32x4 D1 = {0.f, 0.f, 0.f, 0.f}, D2 = {0.f, 0.f, 0.f, 0.f};
          #pragma unroll
          for (int ks = 0; ks < 2; ++ks) {
            bf16x8 a1 = ldfrag(&s_j1[(mt * 16 + l) * 72 + ks * 32 + quad * 8]);
            bf16x8 a2 = ldfrag(&s_j2[(mt * 16 + l) * 72 + ks * 32 + quad * 8]);
            D1 = mfma16(a1, bq2[ks], D1);   // de1_i . de2_j
            D2 = mfma16(a2, bq1[ks], D2);   // de2_i . de1_j
          }
          #pragma unroll
          for (int r = 0; r < 4; ++r) {
            const int i = jh * 128 + mt * 16 + quad * 4 + r;
            float d = ftanh(D1[r] - D2[r]);
            float eN = fmaxf(d, 0.f);
            float old = Ehc[(r0 + l) * N_ + i];
            float dd = eN - old;
            Ehc[(r0 + l) * N_ + i] = eN;
            s_msum[l * 257 + i] += dd;
            dcacc += dd;
          }
        }
      }
      dcacc += __shfl_xor(dcacc, 16);
      dcacc += __shfl_xor(dcacc, 32);
      if (lane < 16) atomicAdd(&s_colv[lane], dcacc);
      __syncthreads();
      if (tid < 16) {
        float nd = s_degacc[tid] + s_colv[tid];
        s_degacc[tid] = nd;
        gst(&degb[r0 + tid], nd);
      }
      __syncthreads();
      ptag(tgDg, wg, (u32)(t + 1));
    }

    // ---------- P4: gates (h-parts pre-poll), dinv/y, s, GRU, h publish ----------
    {
      // precompute z/r h-part MFMAs (depend only on local s_hbf)
      f32x4 azh = {0.f, 0.f, 0.f, 0.f}, arh = {0.f, 0.f, 0.f, 0.f};
      #pragma unroll
      for (int ks = 0; ks < 2; ++ks) {
        bf16x8 afr = ldfrag(&s_hbf[l * 72 + ks * 32 + quad * 8]);
        azh = mfma16(afr, ldfrag(&s_gzT[e * 72 + ks * 32 + quad * 8]), azh);
        arh = mfma16(afr, ldfrag(&s_grT[e * 72 + ks * 32 + quad * 8]), arh);
      }
      wtag(tgDg, (u32)(t + 1));
      const float cnt = (float)((t + 1 < S_) ? (t + 1) : S_);
      const float invc = 1.f / cnt;
      {
        float dg = 1.f + gld(&degb[tid]) * invc;
        float di = rsqrtf(dg);
        float xv = p.xf[((size_t)b * N_ + tid) * T_ + t];
        s_dinv[tid] = di;
        s_y[tid] = di * xv;
      }
      __syncthreads();
      {
        const int jl = tid & 15, c = tid >> 4;
        float part = 0.f;
        #pragma unroll
        for (int k = 0; k < 16; ++k)
          part += s_msum[jl * 257 + c * 16 + k] * s_y[c * 16 + k];
        s_part[c * 16 + jl] = part;
      }
      __syncthreads();
      if (tid < 16) {
        float tot = 0.f;
        for (int k = 0; k < 16; ++k) tot += s_part[k * 16 + tid];
        const int j = r0 + tid;
        s_s[tid] = s_dinv[j] * (tot * invc + s_y[j]);
      }
      __syncthreads();
      float sv[4];
      #pragma unroll
      for (int r = 0; r < 4; ++r) sv[r] = s_s[quad * 4 + r];
      float zz[4], rr2[4];
      #pragma unroll
      for (int r = 0; r < 4; ++r) {
        zz[r]  = fsigm(azh[r] + s_uv[0 * 64 + e] * sv[r] + s_uv[1 * 64 + e]);
        rr2[r] = fsigm(arh[r] + s_uv[2 * 64 + e] * sv[r] + s_uv[3 * 64 + e]);
      }
      #pragma unroll
      for (int r = 0; r < 4; ++r)
        s_dfhr[(quad * 4 + r) * 72 + e] = f2b(hreg[r] * rr2[r]);
      __syncthreads();
      // candidate
      f32x4 ah;
      #pragma unroll
      for (int r = 0; r < 4; ++r) ah[r] = s_uv[4 * 64 + e] * sv[r] + s_uv[5 * 64 + e];
      #pragma unroll
      for (int ks = 0; ks < 2; ++ks) {
        bf16x8 afr = ldfrag(&s_dfhr[l * 72 + ks * 32 + quad * 8]);
        ah = mfma16(afr, ldfrag(&s_ghT[e * 72 + ks * 32 + quad * 8]), ah);
      }
      #pragma unroll
      for (int r = 0; r < 4; ++r) {
        float ht = ftanh(ah[r]);
        hreg[r] = zz[r] * hreg[r] + (1.f - zz[r]) * ht;
      }
      #pragma unroll
      for (int r = 0; r < 4; ++r)
        s_hbf[(quad * 4 + r) * 72 + e] = f2b(hreg[r]);
      if (t == T_ - 1) {
        #pragma unroll
        for (int r = 0; r < 4; ++r)
          hb[(r0 + quad * 4 + r) * 64 + e] = hreg[r];
      }
      __syncthreads();
      // publish h^T strip: hgpT[k][own 4 u64]
      {
        const int k = tid >> 2, c4 = tid & 3;
        u64 v = (u64)s_hbf[(c4 * 4 + 0) * 72 + k]
              | ((u64)s_hbf[(c4 * 4 + 1) * 72 + k] << 16)
              | ((u64)s_hbf[(c4 * 4 + 2) * 72 + k] << 32)
              | ((u64)s_hbf[(c4 * 4 + 3) * 72 + k] << 48);
        gst64(&hgpb[(size_t)k * 64 + (r0 >> 2) + c4], v);
      }
      __syncthreads();
      ptag(tgH, wg, (u32)(t + 1));
    }
  }
}

// ================= classifier =================
__global__ void k_cls(Params p) {
  __shared__ float red[256][4];
  const int b = blockIdx.x, i = threadIdx.x;
  const float* hr = p.h + ((size_t)b * N_ + i) * 64;
  const float* w = p.clswf + (size_t)i * 64 * 4;
  float a0 = 0, a1 = 0, a2 = 0, a3 = 0;
  for (int f = 0; f < 64; ++f) {
    float hv = hr[f];
    a0 += hv * w[f * 4 + 0]; a1 += hv * w[f * 4 + 1];
    a2 += hv * w[f * 4 + 2]; a3 += hv * w[f * 4 + 3];
  }
  red[i][0] = a0; red[i][1] = a1; red[i][2] = a2; red[i][3] = a3;
  __syncthreads();
  for (int st = 128; st > 0; st >>= 1) {
    if (i < st) {
      red[i][0] += red[i + st][0]; red[i][1] += red[i + st][1];
      red[i][2] += red[i + st][2]; red[i][3] += red[i + st][3];
    }
    __syncthreads();
  }
  if (i < 4) {
    float v = red[0][i] + p.clsbf[i];
    if (*p.flag) ((float*)p.out)[b * 4 + i] = v;
    else         ((u16*)p.out)[b * 4 + i] = f2b(v);
  }
}

extern "C" void kernel_launch(void* const* d_in, const int* in_sizes, int n_in,
                              void* d_out, int out_size, void* d_ws, size_t ws_size,
                              hipStream_t stream) {
  float* w = (float*)d_ws;
  size_t o = 0;
  auto alloc = [&](size_t n) { float* r = w + o; o += (n + 63) & ~(size_t)63; return r; };
  float* xf    = alloc(262144);
  float* ewf   = alloc(E_);
  float* gwf   = alloc(FG_ * 64);
  float* gbf   = alloc(64);
  float* b1f   = alloc(64);
  float* b2ff  = alloc(64);
  float* wzcf  = alloc(64); float* bzcf = alloc(64); float* wzlf = alloc(8192); float* bzlf = alloc(64);
  float* wrcf  = alloc(64); float* brcf = alloc(64); float* wrlf = alloc(8192); float* brlf = alloc(64);
  float* whcf  = alloc(64); float* bhcf = alloc(64); float* whlf = alloc(8192); float* bhlf = alloc(64);
  float* clswf = alloc(65536); float* clsbf = alloc(64);
  u16* w1h = (u16*)alloc(2048);
  u16* w2h = (u16*)alloc(2048);
  int* flag = (int*)alloc(64);
  float* AnT   = alloc(65536);
  float* dinvS = alloc(256);
  float* uvF   = alloc(384);
  u64* de1g = (u64*)alloc((size_t)B_ * N_ * 32);   // 16 u64/row
  u64* de2g = (u64*)alloc((size_t)B_ * N_ * 32);
  u64* xTp  = (u64*)alloc((size_t)B_ * 64 * 128);  // 64 u64/row
  const size_t zero_off = o;
  float* Ascr  = alloc((size_t)N_ * N_);
  float* h     = alloc((size_t)B_ * N_ * 64);
  u64*   hgpT  = (u64*)alloc((size_t)B_ * 64 * 128);
  float* degs  = alloc((size_t)B_ * N_);
  u32*   tags  = (u32*)alloc(B_ * 64);             // 256 B per batch
  float* Eh    = alloc((size_t)B_ * S_ * N_ * N_);
  if (ws_size < o * sizeof(float)) return;

  (void)hipMemsetAsync(w + zero_off, 0, (o - zero_off) * sizeof(float), stream);

  Params p;
  p.x0  = d_in[0];  p.ew0 = d_in[1];
  p.gw0 = d_in[2];  p.gb0 = d_in[3];
  p.w10 = d_in[4];  p.b10 = d_in[5];
  p.w20 = d_in[6];  p.b20 = d_in[7];
  p.wzc0 = d_in[8];  p.bzc0 = d_in[9];  p.wzl0 = d_in[10]; p.bzl0 = d_in[11];
  p.wrc0 = d_in[12]; p.brc0 = d_in[13]; p.wrl0 = d_in[14]; p.brl0 = d_in[15];
  p.whc0 = d_in[16]; p.bhc0 = d_in[17]; p.whl0 = d_in[18]; p.bhl0 = d_in[19];
  p.clsw0 = d_in[20]; p.clsb0 = d_in[21];
  p.eidx = (const int*)d_in[22];
  p.xf = xf; p.ewf = ewf; p.gwf = gwf; p.gbf = gbf; p.b1f = b1f; p.b2ff = b2ff;
  p.wzcf = wzcf; p.bzcf = bzcf; p.wzlf = wzlf; p.bzlf = bzlf;
  p.wrcf = wrcf; p.brcf = brcf; p.wrlf = wrlf; p.brlf = brlf;
  p.whcf = whcf; p.bhcf = bhcf; p.whlf = whlf; p.bhlf = bhlf;
  p.clswf = clswf; p.clsbf = clsbf; p.w1h = w1h; p.w2h = w2h;
  p.AnT = AnT; p.dinvS = dinvS; p.uvF = uvF;
  p.h = h; p.degsum = degs; p.Eh = Eh; p.Ascr = Ascr;
  p.de1g = de1g; p.de2g = de2g; p.xTp = xTp; p.hgpT = hgpT;
  p.tags = tags; p.flag = flag; p.out = d_out;

  k_detect<<<1, 64, 0, stream>>>(p);
  k_convert<<<53, 256, 0, stream>>>(p);
  k_xt<<<B_, 256, 0, stream>>>(p);
  k_scatter<<<1, 256, 0, stream>>>(p);
  k_deg<<<1, 256, 0, stream>>>(p);
  k_ant<<<N_, 256, 0, stream>>>(p);
  k_uv<<<1, 64, 0, stream>>>(p);

  void* args[] = { &p };
  hipError_t ce = hipLaunchCooperativeKernel((const void*)dtgcn_main,
                                             dim3(B_ * G_), dim3(256), args, 0, stream);
  if (ce != hipSuccess) {
    (void)hipGetLastError();
    dtgcn_main<<<dim3(B_ * G_), dim3(256), 0, stream>>>(p);
  }

  k_cls<<<B_, 256, 0, stream>>>(p);
}

// Round 15
// 890.884 us; speedup vs baseline: 1.3153x; 1.0671x over previous
//
#include <hip/hip_runtime.h>
#include <hip/hip_bf16.h>

// DTGCN: B=16,N=256,T=64,W=12,H=64,ED=64,S=5,C=4,E=2048, FG=76
// R15: single coop kernel (memset + 1 dispatch). Prologue folds dtype detect,
// weight conversion, WG-local A-normalization (edge scan + LDS atomics),
// x^T build (tag tgX), uv. Tail folds the classifier (tag tgC).
// Step loop: tag dataflow sync with HALF-polls (P3 de halves; phase-A h halves)
// overlapping waits with MFMA work. All MFMA fed from LDS; sc loads batched.

typedef unsigned short u16;
typedef unsigned int u32;
typedef unsigned long long u64;
typedef __attribute__((ext_vector_type(8))) short bf16x8;
typedef __attribute__((ext_vector_type(4))) float f32x4;

#define B_ 16
#define N_ 256
#define T_ 64
#define W_ 12
#define S_ 5
#define E_ 2048
#define G_ 16

__device__ __forceinline__ float b2f(u16 u) {
  union { u32 i; float f; } v; v.i = ((u32)u) << 16; return v.f;
}
__device__ __forceinline__ u16 f2b(float f) {
  union { float f; u32 i; } v; v.f = f;
  u32 x = v.i; x += 0x7fff + ((x >> 16) & 1); return (u16)(x >> 16);
}
__device__ __forceinline__ float ftanh(float x) {
  float e = __expf(-2.f * fabsf(x));
  float t = (1.f - e) / (1.f + e);
  return x < 0.f ? -t : t;
}
__device__ __forceinline__ float fsigm(float x) { return 1.f / (1.f + __expf(-x)); }
__device__ __forceinline__ float cvload(const void* p, size_t i, int f) {
  return f ? ((const float*)p)[i] : b2f(((const u16*)p)[i]);
}
__device__ __forceinline__ u16 cvloadb(const void* p, size_t i, int f) {
  return f ? f2b(((const float*)p)[i]) : ((const u16*)p)[i];
}
__device__ __forceinline__ float gld(const float* p) {
  return __hip_atomic_load(p, __ATOMIC_RELAXED, __HIP_MEMORY_SCOPE_SYSTEM);
}
__device__ __forceinline__ void gst(float* p, float v) {
  __hip_atomic_store(p, v, __ATOMIC_RELAXED, __HIP_MEMORY_SCOPE_SYSTEM);
}
__device__ __forceinline__ u64 gld64(const u64* p) {
  return __hip_atomic_load(p, __ATOMIC_RELAXED, __HIP_MEMORY_SCOPE_SYSTEM);
}
__device__ __forceinline__ void gst64(u64* p, u64 v) {
  __hip_atomic_store(p, v, __ATOMIC_RELAXED, __HIP_MEMORY_SCOPE_SYSTEM);
}
__device__ __forceinline__ u32 gldu(const u32* p) {
  return __hip_atomic_load(p, __ATOMIC_RELAXED, __HIP_MEMORY_SCOPE_SYSTEM);
}
__device__ __forceinline__ f32x4 mfma16(bf16x8 a, bf16x8 b, f32x4 c) {
  return __builtin_amdgcn_mfma_f32_16x16x32_bf16(a, b, c, 0, 0, 0);
}
__device__ __forceinline__ bf16x8 ldfrag(const u16* p) { return *(const bf16x8*)p; }

struct Params {
  const void *x0, *ew0, *gw0, *gb0, *w10, *b10, *w20, *b20;
  const void *wzc0, *bzc0, *wzl0, *bzl0, *wrc0, *brc0, *wrl0, *brl0;
  const void *whc0, *bhc0, *whl0, *bhl0, *clsw0, *clsb0;
  const int* eidx;
  float *degsum, *Eh, *clspart;
  u64 *de1g, *de2g, *xTp, *hgpT;
  u32 *tags;
  void* out;
};

__device__ __forceinline__ void wtag(const u32* tg, u32 target) {
  const int k = threadIdx.x & 15;
  while (!__all((int)(gldu(&tg[k]) >= target)))
    __builtin_amdgcn_s_sleep(1);
}
__device__ __forceinline__ void wtag8(const u32* tg, int base, u32 target) {
  const int k = base + (threadIdx.x & 7);
  while (!__all((int)(gldu(&tg[k]) >= target)))
    __builtin_amdgcn_s_sleep(1);
}
__device__ __forceinline__ void ptag(u32* tg, int wg, u32 val) {
  if (threadIdx.x == 0)
    __hip_atomic_store(&tg[wg], val, __ATOMIC_RELAXED, __HIP_MEMORY_SCOPE_SYSTEM);
}

// ================= main persistent kernel (prologue + loop + cls tail) ======
__global__ void __launch_bounds__(256) dtgcn_main(Params p) {
  __shared__ __align__(16) u16 s_union[21120];   // prologue scratch / ItT[80][264] / j1,j2 / s_part
  __shared__ __align__(16) u16 s_gwF[64 * 104];
  __shared__ __align__(16) u16 s_w1T[64 * 72], s_w2T[64 * 72];
  __shared__ __align__(16) u16 s_gzT[64 * 72], s_grT[64 * 72], s_ghT[64 * 72];
  __shared__ __align__(16) u16 s_antO1[16 * 264], s_antO2[16 * 264];
  __shared__ __align__(16) u16 s_m1[16 * 104];
  __shared__ float s_msum[16 * 257];
  __shared__ __align__(16) u16 s_de1I[16 * 72], s_de2I[16 * 72];
  __shared__ __align__(16) u16 s_hbf[16 * 72];
  __shared__ __align__(16) u16 s_dfhr[16 * 72];
  __shared__ float s_colv[16], s_degacc[16];
  __shared__ float s_y[256], s_dinv[256], s_s[16];
  __shared__ float s_uv[384], s_gb[64], s_b1[64], s_b2[64];
  __shared__ int s_flag;

  const int b = blockIdx.x & 15;
  const int wg = blockIdx.x >> 4;
  const int tid = threadIdx.x;
  const int lane = tid & 63;
  const int wv = tid >> 6;
  const int l = lane & 15;
  const int quad = lane >> 4;
  const int r0 = wg * 16;

  u64* de1g = p.de1g + (size_t)b * N_ * 16;
  u64* de2g = p.de2g + (size_t)b * N_ * 16;
  u64* hgpb = p.hgpT + (size_t)b * 64 * 64;
  u64* xTw  = p.xTp + (size_t)b * 64 * 64;
  const u64* xTb = xTw;
  float* degb = p.degsum + (size_t)b * N_;
  u32* tgDe = p.tags + b * 128;
  u32* tgDg = p.tags + b * 128 + 16;
  u32* tgH  = p.tags + b * 128 + 32;
  u32* tgX  = p.tags + b * 128 + 48;
  u32* tgC  = p.tags + b * 128 + 64;

  // ================= prologue =================
  // 1) dtype detect
  if (tid == 0) {
    const u16* q = (const u16*)p.x0;
    int c = 0;
    for (int i = 0; i < 256; ++i) {
      int ex = (q[i] >> 7) & 0xff;
      c += (ex >= 110 && ex <= 135);
    }
    s_flag = (c < 200) ? 1 : 0;   // 1 = fp32 inputs
  }
  __syncthreads();
  const int fl = s_flag;

  // 2) x^T build: this WG handles t rows [4wg, 4wg+4)
  {
    u16* xs = s_union;   // [4][256]
    #pragma unroll
    for (int r = 0; r < 4; ++r) {
      const int tt = wg * 4 + r;
      xs[r * 256 + tid] = f2b(cvload(p.x0, ((size_t)b * N_ + tid) * T_ + tt, fl));
    }
    __syncthreads();
    const int r = tid >> 6, c = tid & 63;
    u64 v = (u64)xs[r * 256 + 4 * c]
          | ((u64)xs[r * 256 + 4 * c + 1] << 16)
          | ((u64)xs[r * 256 + 4 * c + 2] << 32)
          | ((u64)xs[r * 256 + 4 * c + 3] << 48);
    gst64(&xTw[(size_t)(wg * 4 + r) * 64 + c], v);
    __syncthreads();
    ptag(tgX, wg, 1);
  }

  // 3) WG-local A-normalization (split-bf16 A^T own columns)
  {
    float* s_acol = (float*)s_union;          // [256][16]
    float* s_dg   = (float*)s_union + 4096;   // [256]
    for (int i = tid; i < 4096; i += 256) s_acol[i] = 0.f;
    s_dg[tid] = 0.f;
    __syncthreads();
    for (int e2 = tid; e2 < E_; e2 += 256) {
      const int sN = p.eidx[e2], dN = p.eidx[E_ + e2];
      const float wv2 = cvload(p.ew0, e2, fl);
      atomicAdd(&s_dg[dN], wv2);
      const int dl = dN - r0;
      if (dl >= 0 && dl < 16) atomicAdd(&s_acol[sN * 16 + dl], wv2);
    }
    __syncthreads();
    s_dg[tid] = rsqrtf(1.f + s_dg[tid]);
    __syncthreads();
    for (int idx = tid; idx < 4096; idx += 256) {
      const int jl = idx >> 8, i = idx & 255;
      float a = s_acol[i * 16 + jl] + ((i == r0 + jl) ? 1.f : 0.f);
      float v = s_dg[i] * a * s_dg[r0 + jl];
      u16 hi = f2b(v);
      s_antO1[jl * 264 + i] = hi;
      s_antO2[jl * 264 + i] = f2b(v - b2f(hi));
    }
  }

  // 4) weights / uv / biases / zeroing (no s_union use)
  for (int idx = tid; idx < 64 * 104; idx += 256) {
    const int ee = idx / 104, k = idx - ee * 104;
    u16 v = 0;
    if (k < 64) v = cvloadb(p.gw0, (12 + k) * 64 + ee, fl);
    else if (k < 76) v = cvloadb(p.gw0, (k - 64) * 64 + ee, fl);
    s_gwF[ee * 104 + k] = v;
  }
  for (int idx = tid; idx < 4096; idx += 256) {
    const int ee = idx >> 6, ff = idx & 63;
    s_w1T[ee * 72 + ff] = cvloadb(p.w10, ff * 64 + ee, fl);
    s_w2T[ee * 72 + ff] = cvloadb(p.w20, ff * 64 + ee, fl);
    s_gzT[ee * 72 + ff] = cvloadb(p.wzl0, 4096 + ff * 64 + ee, fl);
    s_grT[ee * 72 + ff] = cvloadb(p.wrl0, 4096 + ff * 64 + ee, fl);
    s_ghT[ee * 72 + ff] = cvloadb(p.whl0, 4096 + ff * 64 + ee, fl);
  }
  if (tid < 64) {
    const int e2 = tid;
    float uz = 0, vz = 0, ur = 0, vr = 0, uh = 0, vh = 0;
    for (int f = 0; f < 64; ++f) {
      float wz = cvload(p.wzl0, f * 64 + e2, fl);
      float wr = cvload(p.wrl0, f * 64 + e2, fl);
      float wh = cvload(p.whl0, f * 64 + e2, fl);
      uz += cvload(p.wzc0, f, fl) * wz; vz += cvload(p.bzc0, f, fl) * wz;
      ur += cvload(p.wrc0, f, fl) * wr; vr += cvload(p.brc0, f, fl) * wr;
      uh += cvload(p.whc0, f, fl) * wh; vh += cvload(p.bhc0, f, fl) * wh;
    }
    s_uv[0 * 64 + e2] = uz; s_uv[1 * 64 + e2] = vz + cvload(p.bzl0, e2, fl);
    s_uv[2 * 64 + e2] = ur; s_uv[3 * 64 + e2] = vr + cvload(p.brl0, e2, fl);
    s_uv[4 * 64 + e2] = uh; s_uv[5 * 64 + e2] = vh + cvload(p.bhl0, e2, fl);
    s_gb[tid] = cvload(p.gb0, tid, fl);
    s_b1[tid] = cvload(p.b10, tid, fl);
    s_b2[tid] = cvload(p.b20, tid, fl);
  }
  for (int idx = tid; idx < 16 * 257; idx += 256) s_msum[idx] = 0.f;
  for (int idx = tid; idx < 16 * 72; idx += 256) s_hbf[idx] = 0;
  for (int idx = tid; idx < 16 * 104; idx += 256) s_m1[idx] = 0;
  for (int idx = 20064 + tid; idx < 21120; idx += 256) s_union[idx] = 0;  // ItT pad rows
  if (tid < 16) s_degacc[tid] = 0.f;
  __syncthreads();

  u16* s_itT = s_union;                 // [80][264]
  u16* s_j1  = s_union;                 // [128][72]
  u16* s_j2  = s_union + 9216;
  float* s_part = (float*)s_union;

  float hreg[4] = {0.f, 0.f, 0.f, 0.f};
  const int e = wv * 16 + l;

  for (int t = 0; t < T_; ++t) {
    // ---------- phase A (halved): stage ItT cols, M1, df, de ----------
    {
      if (t == 0) wtag(tgX, 1);
      // x-window regs for both halves (no h dependency)
      u64 tw0[2], tw1[2];
      #pragma unroll
      for (int q = 0; q < 2; ++q) {
        const int idx = q * 256 + tid;
        const int row = idx >> 5, c = idx & 31;
        const bool ok = idx < 384;
        const int tx = t - (W_ - 1) + row;
        const bool live = ok && tx >= 0;
        tw0[q] = live ? gld64(&xTb[(size_t)tx * 64 + c]) : 0ull;
        tw1[q] = live ? gld64(&xTb[(size_t)tx * 64 + 32 + c]) : 0ull;
      }
      f32x4 accA[2];
      accA[0] = (f32x4){0.f, 0.f, 0.f, 0.f};
      accA[1] = (f32x4){0.f, 0.f, 0.f, 0.f};
      // half 0: h cols 0..127 (tags 0..7)
      wtag8(tgH, 0, (u32)t);
      {
        u64 th[8];
        #pragma unroll
        for (int q = 0; q < 8; ++q) {
          const int idx = q * 256 + tid;
          const int row = idx >> 5, c = idx & 31;
          th[q] = gld64(&hgpb[(size_t)row * 64 + c]);
        }
        #pragma unroll
        for (int q = 0; q < 8; ++q) {
          const int idx = q * 256 + tid;
          const int row = idx >> 5, c = idx & 31;
          *(u64*)&s_itT[row * 264 + c * 4] = th[q];
        }
        #pragma unroll
        for (int q = 0; q < 2; ++q) {
          const int idx = q * 256 + tid;
          if (idx < 384) {
            const int row = idx >> 5, c = idx & 31;
            *(u64*)&s_itT[(64 + row) * 264 + c * 4] = tw0[q];
          }
        }
      }
      __syncthreads();
      {
        int ti = 0;
        for (int nt = wv; nt < 5; nt += 4, ++ti) {
          #pragma unroll
          for (int ch = 0; ch < 4; ++ch) {
            const int io = ch * 32 + quad * 8;
            bf16x8 bfr = ldfrag(&s_itT[(nt * 16 + l) * 264 + io]);
            accA[ti] = mfma16(ldfrag(&s_antO1[l * 264 + io]), bfr, accA[ti]);
            accA[ti] = mfma16(ldfrag(&s_antO2[l * 264 + io]), bfr, accA[ti]);
          }
        }
      }
      // half 1: h cols 128..255 (tags 8..15)
      wtag8(tgH, 8, (u32)t);
      {
        u64 th[8];
        #pragma unroll
        for (int q = 0; q < 8; ++q) {
          const int idx = q * 256 + tid;
          const int row = idx >> 5, c = idx & 31;
          th[q] = gld64(&hgpb[(size_t)row * 64 + 32 + c]);
        }
        __syncthreads();   // half-0 MFMA reads done before overwriting? cols disjoint; sync guards store/read order across waves
        #pragma unroll
        for (int q = 0; q < 8; ++q) {
          const int idx = q * 256 + tid;
          const int row = idx >> 5, c = idx & 31;
          *(u64*)&s_itT[row * 264 + (32 + c) * 4] = th[q];
        }
        #pragma unroll
        for (int q = 0; q < 2; ++q) {
          const int idx = q * 256 + tid;
          if (idx < 384) {
            const int row = idx >> 5, c = idx & 31;
            *(u64*)&s_itT[(64 + row) * 264 + (32 + c) * 4] = tw1[q];
          }
        }
      }
      __syncthreads();
      {
        int ti = 0;
        for (int nt = wv; nt < 5; nt += 4, ++ti) {
          #pragma unroll
          for (int ch = 4; ch < 8; ++ch) {
            const int io = ch * 32 + quad * 8;
            bf16x8 bfr = ldfrag(&s_itT[(nt * 16 + l) * 264 + io]);
            accA[ti] = mfma16(ldfrag(&s_antO1[l * 264 + io]), bfr, accA[ti]);
            accA[ti] = mfma16(ldfrag(&s_antO2[l * 264 + io]), bfr, accA[ti]);
          }
          #pragma unroll
          for (int r = 0; r < 4; ++r)
            s_m1[(quad * 4 + r) * 104 + nt * 16 + l] = f2b(accA[ti][r]);
        }
      }
      __syncthreads();
      // df = M1 @ gw + gb (K=96, cols>=80 zero)
      {
        f32x4 dfa = {0.f, 0.f, 0.f, 0.f};
        #pragma unroll
        for (int ks = 0; ks < 3; ++ks) {
          bf16x8 afr = ldfrag(&s_m1[l * 104 + ks * 32 + quad * 8]);
          dfa = mfma16(afr, ldfrag(&s_gwF[e * 104 + ks * 32 + quad * 8]), dfa);
        }
        #pragma unroll
        for (int r = 0; r < 4; ++r)
          s_dfhr[(quad * 4 + r) * 72 + e] = f2b(dfa[r] + s_gb[e]);
      }
      __syncthreads();
      // de1/de2
      {
        f32x4 E1, E2;
        #pragma unroll
        for (int r = 0; r < 4; ++r) { E1[r] = s_b1[e]; E2[r] = s_b2[e]; }
        #pragma unroll
        for (int ks = 0; ks < 2; ++ks) {
          bf16x8 afr = ldfrag(&s_dfhr[l * 72 + ks * 32 + quad * 8]);
          E1 = mfma16(afr, ldfrag(&s_w1T[e * 72 + ks * 32 + quad * 8]), E1);
          E2 = mfma16(afr, ldfrag(&s_w2T[e * 72 + ks * 32 + quad * 8]), E2);
        }
        #pragma unroll
        for (int r = 0; r < 4; ++r) {
          s_de1I[(quad * 4 + r) * 72 + e] = f2b(ftanh(E1[r]));
          s_de2I[(quad * 4 + r) * 72 + e] = f2b(ftanh(E2[r]));
        }
      }
      __syncthreads();
      // publish de strips
      {
        const int row = tid >> 4, c = tid & 15;
        u64 v1 = *(const u64*)&s_de1I[row * 72 + c * 4];
        u64 v2 = *(const u64*)&s_de2I[row * 72 + c * 4];
        gst64(&de1g[(size_t)(r0 + row) * 16 + c], v1);
        gst64(&de2g[(size_t)(r0 + row) * 16 + c], v2);
      }
      __syncthreads();
      ptag(tgDe, wg, (u32)(t + 1));
    }

    // ---------- P3: Et column strip, half-polled; Eh/Msum/deg ----------
    {
      const int sidx = t % S_;
      float* Ehc = p.Eh + (size_t)(b * S_ + sidx) * N_ * N_;
      if (tid < 16) s_colv[tid] = 0.f;
      bf16x8 bq1[2], bq2[2];
      #pragma unroll
      for (int ks = 0; ks < 2; ++ks) {
        bq1[ks] = ldfrag(&s_de1I[l * 72 + ks * 32 + quad * 8]);
        bq2[ks] = ldfrag(&s_de2I[l * 72 + ks * 32 + quad * 8]);
      }
      float dcacc = 0.f;
      for (int jh = 0; jh < 2; ++jh) {
        wtag8(tgDe, jh * 8, (u32)(t + 1));
        u64 t1[8], t2[8];
        #pragma unroll
        for (int q = 0; q < 8; ++q) {
          const int idx = q * 256 + tid;
          const int row = idx >> 4, c = idx & 15;
          t1[q] = gld64(&de1g[(size_t)(jh * 128 + row) * 16 + c]);
          t2[q] = gld64(&de2g[(size_t)(jh * 128 + row) * 16 + c]);
        }
        __syncthreads();
        #pragma unroll
        for (int q = 0; q < 8; ++q) {
          const int idx = q * 256 + tid;
          const int row = idx >> 4, c = idx & 15;
          *(u64*)&s_j1[row * 72 + c * 4] = t1[q];
          *(u64*)&s_j2[row * 72 + c * 4] = t2[q];
        }
        __syncthreads();
        #pragma unroll
        for (int mt2 = 0; mt2 < 2; ++mt2) {
          const int mt = wv * 2 + mt2;
          f32x4 D1 = {0.f, 0.f, 0.f, 0.f}, D2 = {0.f, 0.f, 0.f, 0.f};
          #pragma unroll
          for (int ks = 0; ks < 2; ++ks) {
            bf16x8 a1 = ldfrag(&s_j1[(mt * 16 + l) * 72 + ks * 32 + quad * 8]);
            bf16x8 a2 = ldfrag(&s_j2[(mt * 16 + l) * 72 + ks * 32 + quad * 8]);
            D1 = mfma16(a1, bq2[ks], D1);
            D2 = mfma16(a2, bq1[ks], D2);
          }
          #pragma unroll
          for (int r = 0; r < 4; ++r) {
            const int i = jh * 128 + mt * 16 + quad * 4 + r;
            float d = ftanh(D1[r] - D2[r]);
            float eN = fmaxf(d, 0.f);
            float old = Ehc[(r0 + l) * N_ + i];
            float dd = eN - old;
            Ehc[(r0 + l) * N_ + i] = eN;
            s_msum[l * 257 + i] += dd;
            dcacc += dd;
          }
        }
      }
      dcacc += __shfl_xor(dcacc, 16);
      dcacc += __shfl_xor(dcacc, 32);
      if (lane < 16) atomicAdd(&s_colv[lane], dcacc);
      __syncthreads();
      if (tid < 16) {
        float nd = s_degacc[tid] + s_colv[tid];
        s_degacc[tid] = nd;
        gst(&degb[r0 + tid], nd);
      }
      __syncthreads();
      ptag(tgDg, wg, (u32)(t + 1));
    }

    // ---------- P4: gates (h-parts pre-poll), dinv/y, s, GRU, h publish ----------
    {
      f32x4 azh = {0.f, 0.f, 0.f, 0.f}, arh = {0.f, 0.f, 0.f, 0.f};
      #pragma unroll
      for (int ks = 0; ks < 2; ++ks) {
        bf16x8 afr = ldfrag(&s_hbf[l * 72 + ks * 32 + quad * 8]);
        azh = mfma16(afr, ldfrag(&s_gzT[e * 72 + ks * 32 + quad * 8]), azh);
        arh = mfma16(afr, ldfrag(&s_grT[e * 72 + ks * 32 + quad * 8]), arh);
      }
      wtag(tgDg, (u32)(t + 1));
      const float cnt = (float)((t + 1 < S_) ? (t + 1) : S_);
      const float invc = 1.f / cnt;
      {
        float dg = 1.f + gld(&degb[tid]) * invc;
        float di = rsqrtf(dg);
        float xv = cvload(p.x0, ((size_t)b * N_ + tid) * T_ + t, fl);
        s_dinv[tid] = di;
        s_y[tid] = di * xv;
      }
      __syncthreads();
      {
        const int jl = tid & 15, c = tid >> 4;
        float part = 0.f;
        #pragma unroll
        for (int k = 0; k < 16; ++k)
          part += s_msum[jl * 257 + c * 16 + k] * s_y[c * 16 + k];
        s_part[c * 16 + jl] = part;
      }
      __syncthreads();
      if (tid < 16) {
        float tot = 0.f;
        for (int k = 0; k < 16; ++k) tot += s_part[k * 16 + tid];
        const int j = r0 + tid;
        s_s[tid] = s_dinv[j] * (tot * invc + s_y[j]);
      }
      __syncthreads();
      float sv[4];
      #pragma unroll
      for (int r = 0; r < 4; ++r) sv[r] = s_s[quad * 4 + r];
      float zz[4], rr2[4];
      #pragma unroll
      for (int r = 0; r < 4; ++r) {
        zz[r]  = fsigm(azh[r] + s_uv[0 * 64 + e] * sv[r] + s_uv[1 * 64 + e]);
        rr2[r] = fsigm(arh[r] + s_uv[2 * 64 + e] * sv[r] + s_uv[3 * 64 + e]);
      }
      #pragma unroll
      for (int r = 0; r < 4; ++r)
        s_dfhr[(quad * 4 + r) * 72 + e] = f2b(hreg[r] * rr2[r]);
      __syncthreads();
      f32x4 ah;
      #pragma unroll
      for (int r = 0; r < 4; ++r) ah[r] = s_uv[4 * 64 + e] * sv[r] + s_uv[5 * 64 + e];
      #pragma unroll
      for (int ks = 0; ks < 2; ++ks) {
        bf16x8 afr = ldfrag(&s_dfhr[l * 72 + ks * 32 + quad * 8]);
        ah = mfma16(afr, ldfrag(&s_ghT[e * 72 + ks * 32 + quad * 8]), ah);
      }
      #pragma unroll
      for (int r = 0; r < 4; ++r) {
        float ht = ftanh(ah[r]);
        hreg[r] = zz[r] * hreg[r] + (1.f - zz[r]) * ht;
      }
      #pragma unroll
      for (int r = 0; r < 4; ++r)
        s_hbf[(quad * 4 + r) * 72 + e] = f2b(hreg[r]);
      __syncthreads();
      {
        const int k = tid >> 2, c4 = tid & 3;
        u64 v = (u64)s_hbf[(c4 * 4 + 0) * 72 + k]
              | ((u64)s_hbf[(c4 * 4 + 1) * 72 + k] << 16)
              | ((u64)s_hbf[(c4 * 4 + 2) * 72 + k] << 32)
              | ((u64)s_hbf[(c4 * 4 + 3) * 72 + k] << 48);
        gst64(&hgpb[(size_t)k * 64 + (r0 >> 2) + c4], v);
      }
      __syncthreads();
      ptag(tgH, wg, (u32)(t + 1));
    }
  }

  // ================= classifier tail =================
  {
    // per-thread partial over own rows (quad*4+r) x col e
    float part[4] = {0.f, 0.f, 0.f, 0.f};
    #pragma unroll
    for (int r = 0; r < 4; ++r) {
      const size_t base = ((size_t)(r0 + quad * 4 + r) * 64 + e) * 4;
      #pragma unroll
      for (int c = 0; c < 4; ++c)
        part[c] += hreg[r] * cvload(p.clsw0, base + c, fl);
    }
    #pragma unroll
    for (int c = 0; c < 4; ++c) {
      float v = part[c];
      v += __shfl_xor(v, 1);  v += __shfl_xor(v, 2);
      v += __shfl_xor(v, 4);  v += __shfl_xor(v, 8);
      v += __shfl_xor(v, 16); v += __shfl_xor(v, 32);
      if (lane == 0) s_s[wv * 4 + c] = v;
    }
    __syncthreads();
    if (tid < 4) {
      float tot = s_s[0 + tid] + s_s[4 + tid] + s_s[8 + tid] + s_s[12 + tid];
      gst(&p.clspart[(b * 16 + wg) * 4 + tid], tot);
    }
    __syncthreads();
    ptag(tgC, wg, 1);
    if (wg == 0) {
      wtag(tgC, 1);
      if (tid < 4) {
        float v = 0.f;
        for (int k = 0; k < 16; ++k) v += gld(&p.clspart[(b * 16 + k) * 4 + tid]);
        v += cvload(p.clsb0, tid, fl);
        if (fl) ((float*)p.out)[b * 4 + tid] = v;
        else    ((u16*)p.out)[b * 4 + tid] = f2b(v);
      }
    }
  }
}

extern "C" void kernel_launch(void* const* d_in, const int* in_sizes, int n_in,
                              void* d_out, int out_size, void* d_ws, size_t ws_size,
                              hipStream_t stream) {
  float* w = (float*)d_ws;
  size_t o = 0;
  auto alloc = [&](size_t n) { float* r = w + o; o += (n + 63) & ~(size_t)63; return r; };
  u64* de1g = (u64*)alloc((size_t)B_ * N_ * 32);   // 16 u64/row
  u64* de2g = (u64*)alloc((size_t)B_ * N_ * 32);
  u64* xTp  = (u64*)alloc((size_t)B_ * 64 * 128);  // 64 u64/row
  float* clspart = alloc(B_ * 16 * 4);
  const size_t zero_off = o;
  u64*   hgpT  = (u64*)alloc((size_t)B_ * 64 * 128);
  float* degs  = alloc((size_t)B_ * N_);
  u32*   tags  = (u32*)alloc(B_ * 128);            // 512 B per batch
  float* Eh    = alloc((size_t)B_ * S_ * N_ * N_);
  if (ws_size < o * sizeof(float)) return;

  (void)hipMemsetAsync(w + zero_off, 0, (o - zero_off) * sizeof(float), stream);

  Params p;
  p.x0  = d_in[0];  p.ew0 = d_in[1];
  p.gw0 = d_in[2];  p.gb0 = d_in[3];
  p.w10 = d_in[4];  p.b10 = d_in[5];
  p.w20 = d_in[6];  p.b20 = d_in[7];
  p.wzc0 = d_in[8];  p.bzc0 = d_in[9];  p.wzl0 = d_in[10]; p.bzl0 = d_in[11];
  p.wrc0 = d_in[12]; p.brc0 = d_in[13]; p.wrl0 = d_in[14]; p.brl0 = d_in[15];
  p.whc0 = d_in[16]; p.bhc0 = d_in[17]; p.whl0 = d_in[18]; p.bhl0 = d_in[19];
  p.clsw0 = d_in[20]; p.clsb0 = d_in[21];
  p.eidx = (const int*)d_in[22];
  p.degsum = degs; p.Eh = Eh; p.clspart = clspart;
  p.de1g = de1g; p.de2g = de2g; p.xTp = xTp; p.hgpT = hgpT;
  p.tags = tags; p.out = d_out;

  void* args[] = { &p };
  hipError_t ce = hipLaunchCooperativeKernel((const void*)dtgcn_main,
                                             dim3(B_ * G_), dim3(256), args, 0, stream);
  if (ce != hipSuccess) {
    (void)hipGetLastError();
    dtgcn_main<<<dim3(B_ * G_), dim3(256), 0, stream>>>(p);
  }
}